// Round 1
// baseline (2855.023 us; speedup 1.0000x reference)
//
#include <hip/hip_runtime.h>
#include <math.h>

constexpr int N = 100000;
constexpr int E = 1600000;
constexpr int C = 128;

// ---------------------------------------------------------------- degree ---
__global__ __launch_bounds__(256) void k_deg(const int* __restrict__ ei,
                                             int* __restrict__ deg) {
    int e = blockIdx.x * 256 + threadIdx.x;
    if (e < E) {
        atomicAdd(&deg[ei[e]], 1);
        atomicAdd(&deg[ei[E + e]], 1);
    }
}

__global__ __launch_bounds__(256) void k_dinv(const int* __restrict__ deg,
                                              float* __restrict__ dinv) {
    int n = blockIdx.x * 256 + threadIdx.x;
    if (n < N) dinv[n] = rsqrtf((float)deg[n] + 1.0f);
}

// ------------------------------------------------------------------ GEMM ---
// xw = x @ W ; out = dinv^2 * xw + b   (self-loop + bias fused here)
// Block: 256 threads, tile 64 rows x 128 cols, K staged in chunks of 32.
__global__ __launch_bounds__(256) void k_gemm(const float* __restrict__ x,
                                              const float* __restrict__ W,
                                              const float* __restrict__ b,
                                              const float* __restrict__ dinv,
                                              float* __restrict__ xw,
                                              float* __restrict__ out) {
    __shared__ float Ws[32][128];   // 16 KB
    __shared__ float xs[64][33];    // pad +1: breaks 16-way bank conflict

    const int t   = threadIdx.x;
    const int r0  = (t & 15) * 4;   // 4 rows per thread
    const int c0  = (t >> 4) * 8;   // 8 cols per thread
    const int bid = blockIdx.x;

    float acc[4][8];
#pragma unroll
    for (int i = 0; i < 4; ++i)
#pragma unroll
        for (int j = 0; j < 8; ++j) acc[i][j] = 0.0f;

    const int lrow = t >> 2;          // 0..63 (row for staging loads)
    const int lk   = (t & 3) * 8;     // 0,8,16,24 within k-chunk
    const long grow = (long)bid * 64 + lrow;
    const bool rvalid = grow < N;

    for (int k0 = 0; k0 < C; k0 += 32) {
        // stage W chunk (32x128 = 1024 float4)
        const float4* Wg = (const float4*)(W + (size_t)k0 * C);
        float4* Wsv = (float4*)(&Ws[0][0]);
#pragma unroll
        for (int j = 0; j < 4; ++j) Wsv[t + 256 * j] = Wg[t + 256 * j];
        // stage x chunk (64 rows x 32 k)
        float4 a0 = {0, 0, 0, 0}, a1 = {0, 0, 0, 0};
        if (rvalid) {
            a0 = *(const float4*)(x + grow * C + k0 + lk);
            a1 = *(const float4*)(x + grow * C + k0 + lk + 4);
        }
        xs[lrow][lk + 0] = a0.x; xs[lrow][lk + 1] = a0.y;
        xs[lrow][lk + 2] = a0.z; xs[lrow][lk + 3] = a0.w;
        xs[lrow][lk + 4] = a1.x; xs[lrow][lk + 5] = a1.y;
        xs[lrow][lk + 6] = a1.z; xs[lrow][lk + 7] = a1.w;
        __syncthreads();

#pragma unroll 8
        for (int k = 0; k < 32; ++k) {
            float4 w0 = *(const float4*)&Ws[k][c0];
            float4 w1 = *(const float4*)&Ws[k][c0 + 4];
            float xv[4];
#pragma unroll
            for (int i = 0; i < 4; ++i) xv[i] = xs[r0 + i][k];
#pragma unroll
            for (int i = 0; i < 4; ++i) {
                acc[i][0] = fmaf(xv[i], w0.x, acc[i][0]);
                acc[i][1] = fmaf(xv[i], w0.y, acc[i][1]);
                acc[i][2] = fmaf(xv[i], w0.z, acc[i][2]);
                acc[i][3] = fmaf(xv[i], w0.w, acc[i][3]);
                acc[i][4] = fmaf(xv[i], w1.x, acc[i][4]);
                acc[i][5] = fmaf(xv[i], w1.y, acc[i][5]);
                acc[i][6] = fmaf(xv[i], w1.z, acc[i][6]);
                acc[i][7] = fmaf(xv[i], w1.w, acc[i][7]);
            }
        }
        __syncthreads();
    }

    const float4 b0 = *(const float4*)(b + c0);
    const float4 b1 = *(const float4*)(b + c0 + 4);
#pragma unroll
    for (int i = 0; i < 4; ++i) {
        long r = (long)bid * 64 + r0 + i;
        if (r >= N) break;
        float s = dinv[r];
        s = s * s;
        float4 v0 = {acc[i][0], acc[i][1], acc[i][2], acc[i][3]};
        float4 v1 = {acc[i][4], acc[i][5], acc[i][6], acc[i][7]};
        *(float4*)(xw + r * C + c0)     = v0;
        *(float4*)(xw + r * C + c0 + 4) = v1;
        float4 o0 = {fmaf(s, v0.x, b0.x), fmaf(s, v0.y, b0.y),
                     fmaf(s, v0.z, b0.z), fmaf(s, v0.w, b0.w)};
        float4 o1 = {fmaf(s, v1.x, b1.x), fmaf(s, v1.y, b1.y),
                     fmaf(s, v1.z, b1.z), fmaf(s, v1.w, b1.w)};
        *(float4*)(out + r * C + c0)     = o0;
        *(float4*)(out + r * C + c0 + 4) = o1;
    }
}

// --------------------------------------------------------------- scatter ---
// One wave per undirected edge; lane handles channels 2*lane, 2*lane+1.
__global__ __launch_bounds__(256) void k_scatter(const int* __restrict__ ei,
                                                 const float* __restrict__ dinv,
                                                 const float* __restrict__ xw,
                                                 float* __restrict__ out) {
    int e = blockIdx.x * 4 + (threadIdx.x >> 6);
    if (e >= E) return;
    int lane = threadIdx.x & 63;
    int u = ei[e];
    int v = ei[E + e];
    float norm = dinv[u] * dinv[v];
    float2 a  = *(const float2*)(xw + (size_t)u * C + 2 * lane);
    float2 bb = *(const float2*)(xw + (size_t)v * C + 2 * lane);
    float* ou = out + (size_t)u * C + 2 * lane;
    float* ov = out + (size_t)v * C + 2 * lane;
    atomicAdd(&ov[0], norm * a.x);
    atomicAdd(&ov[1], norm * a.y);
    atomicAdd(&ou[0], norm * bb.x);
    atomicAdd(&ou[1], norm * bb.y);
}

// ---------------------------------------------------------------- launch ---
extern "C" void kernel_launch(void* const* d_in, const int* in_sizes, int n_in,
                              void* d_out, int out_size, void* d_ws, size_t ws_size,
                              hipStream_t stream) {
    const float* x  = (const float*)d_in[0];
    const float* W  = (const float*)d_in[1];
    const float* b  = (const float*)d_in[2];
    const int*   ei = (const int*)d_in[3];
    float* out = (float*)d_out;

    // workspace layout: xw [N*C f32] | deg [N i32] | dinv [N f32]
    float* xw   = (float*)d_ws;
    int*   deg  = (int*)((char*)d_ws + (size_t)N * C * sizeof(float));
    float* dinv = (float*)(deg + N);

    hipMemsetAsync(deg, 0, N * sizeof(int), stream);
    k_deg<<<(E + 255) / 256, 256, 0, stream>>>(ei, deg);
    k_dinv<<<(N + 255) / 256, 256, 0, stream>>>(deg, dinv);
    k_gemm<<<(N + 63) / 64, 256, 0, stream>>>(x, W, b, dinv, xw, out);
    k_scatter<<<E / 4, 256, 0, stream>>>(ei, dinv, xw, out);
}

// Round 2
// 990.044 us; speedup vs baseline: 2.8837x; 2.8837x over previous
//
#include <hip/hip_runtime.h>
#include <math.h>

constexpr int N = 100000;
constexpr int E = 1600000;
constexpr int C = 128;

// ---------------------------------------------------------------- degree ---
__global__ __launch_bounds__(256) void k_deg(const int* __restrict__ ei,
                                             int* __restrict__ deg) {
    int e = blockIdx.x * 256 + threadIdx.x;
    if (e < E) {
        atomicAdd(&deg[ei[e]], 1);
        atomicAdd(&deg[ei[E + e]], 1);
    }
}

__global__ __launch_bounds__(256) void k_dinv(const int* __restrict__ deg,
                                              float* __restrict__ dinv) {
    int n = blockIdx.x * 256 + threadIdx.x;
    if (n < N) dinv[n] = rsqrtf((float)deg[n] + 1.0f);
}

// ------------------------------------------------------- exclusive scan ----
// Single 1024-thread block; each thread owns a contiguous chunk of 98 nodes.
__global__ __launch_bounds__(1024) void k_scan(const int* __restrict__ deg,
                                               int* __restrict__ rowptr) {
    __shared__ int part[1024];
    const int t = threadIdx.x;
    const int CH = (N + 1023) >> 10;  // 98
    const int base = t * CH;
    int s = 0;
    for (int i = 0; i < CH; ++i) {
        int idx = base + i;
        if (idx < N) s += deg[idx];
    }
    part[t] = s;
    __syncthreads();
    for (int off = 1; off < 1024; off <<= 1) {
        int add = (t >= off) ? part[t - off] : 0;
        __syncthreads();
        part[t] += add;
        __syncthreads();
    }
    int run = (t == 0) ? 0 : part[t - 1];
    for (int i = 0; i < CH; ++i) {
        int idx = base + i;
        if (idx < N) { rowptr[idx] = run; run += deg[idx]; }
    }
}

// ------------------------------------------------------------- CSR fill ----
// Destroys rowptr: after this, rowptr[u] == end of u's segment.
__global__ __launch_bounds__(256) void k_fill(const int* __restrict__ ei,
                                              int* __restrict__ cursor,
                                              int* __restrict__ adj) {
    int e = blockIdx.x * 256 + threadIdx.x;
    if (e >= E) return;
    int u = ei[e], v = ei[E + e];
    adj[atomicAdd(&cursor[u], 1)] = v;
    adj[atomicAdd(&cursor[v], 1)] = u;
}

// ------------------------------------------------------------------ GEMM ---
// xw = x @ W ; out = dinv^2 * xw + b   (self-loop + bias fused here)
__global__ __launch_bounds__(256) void k_gemm(const float* __restrict__ x,
                                              const float* __restrict__ W,
                                              const float* __restrict__ b,
                                              const float* __restrict__ dinv,
                                              float* __restrict__ xw,
                                              float* __restrict__ out) {
    __shared__ float Ws[32][128];   // 16 KB
    __shared__ float xs[64][33];    // pad +1: breaks bank conflicts

    const int t   = threadIdx.x;
    const int r0  = (t & 15) * 4;   // 4 rows per thread
    const int c0  = (t >> 4) * 8;   // 8 cols per thread
    const int bid = blockIdx.x;

    float acc[4][8];
#pragma unroll
    for (int i = 0; i < 4; ++i)
#pragma unroll
        for (int j = 0; j < 8; ++j) acc[i][j] = 0.0f;

    const int lrow = t >> 2;
    const int lk   = (t & 3) * 8;
    const long grow = (long)bid * 64 + lrow;
    const bool rvalid = grow < N;

    for (int k0 = 0; k0 < C; k0 += 32) {
        const float4* Wg = (const float4*)(W + (size_t)k0 * C);
        float4* Wsv = (float4*)(&Ws[0][0]);
#pragma unroll
        for (int j = 0; j < 4; ++j) Wsv[t + 256 * j] = Wg[t + 256 * j];
        float4 a0 = {0, 0, 0, 0}, a1 = {0, 0, 0, 0};
        if (rvalid) {
            a0 = *(const float4*)(x + grow * C + k0 + lk);
            a1 = *(const float4*)(x + grow * C + k0 + lk + 4);
        }
        xs[lrow][lk + 0] = a0.x; xs[lrow][lk + 1] = a0.y;
        xs[lrow][lk + 2] = a0.z; xs[lrow][lk + 3] = a0.w;
        xs[lrow][lk + 4] = a1.x; xs[lrow][lk + 5] = a1.y;
        xs[lrow][lk + 6] = a1.z; xs[lrow][lk + 7] = a1.w;
        __syncthreads();

#pragma unroll 8
        for (int k = 0; k < 32; ++k) {
            float4 w0 = *(const float4*)&Ws[k][c0];
            float4 w1 = *(const float4*)&Ws[k][c0 + 4];
            float xv[4];
#pragma unroll
            for (int i = 0; i < 4; ++i) xv[i] = xs[r0 + i][k];
#pragma unroll
            for (int i = 0; i < 4; ++i) {
                acc[i][0] = fmaf(xv[i], w0.x, acc[i][0]);
                acc[i][1] = fmaf(xv[i], w0.y, acc[i][1]);
                acc[i][2] = fmaf(xv[i], w0.z, acc[i][2]);
                acc[i][3] = fmaf(xv[i], w0.w, acc[i][3]);
                acc[i][4] = fmaf(xv[i], w1.x, acc[i][4]);
                acc[i][5] = fmaf(xv[i], w1.y, acc[i][5]);
                acc[i][6] = fmaf(xv[i], w1.z, acc[i][6]);
                acc[i][7] = fmaf(xv[i], w1.w, acc[i][7]);
            }
        }
        __syncthreads();
    }

    const float4 b0 = *(const float4*)(b + c0);
    const float4 b1 = *(const float4*)(b + c0 + 4);
#pragma unroll
    for (int i = 0; i < 4; ++i) {
        long r = (long)bid * 64 + r0 + i;
        if (r >= N) break;
        float s = dinv[r];
        s = s * s;
        float4 v0 = {acc[i][0], acc[i][1], acc[i][2], acc[i][3]};
        float4 v1 = {acc[i][4], acc[i][5], acc[i][6], acc[i][7]};
        *(float4*)(xw + r * C + c0)     = v0;
        *(float4*)(xw + r * C + c0 + 4) = v1;
        float4 o0 = {fmaf(s, v0.x, b0.x), fmaf(s, v0.y, b0.y),
                     fmaf(s, v0.z, b0.z), fmaf(s, v0.w, b0.w)};
        float4 o1 = {fmaf(s, v1.x, b1.x), fmaf(s, v1.y, b1.y),
                     fmaf(s, v1.z, b1.z), fmaf(s, v1.w, b1.w)};
        *(float4*)(out + r * C + c0)     = o0;
        *(float4*)(out + r * C + c0 + 4) = o1;
    }
}

// ---------------------------------------------------------------- gather ---
// One wave per node; lane handles channels 2*lane, 2*lane+1. No atomics.
// rowend[u] = end of u's CSR segment (post-fill rowptr); start = end - deg[u].
__global__ __launch_bounds__(256) void k_gather(const int* __restrict__ rowend,
                                                const int* __restrict__ deg,
                                                const float* __restrict__ dinv,
                                                const int* __restrict__ adj,
                                                const float* __restrict__ xw,
                                                float* __restrict__ out) {
    int u = blockIdx.x * 4 + (threadIdx.x >> 6);
    if (u >= N) return;
    const int lane = threadIdx.x & 63;
    const int d = deg[u];
    if (d == 0) return;
    const int start = rowend[u] - d;
    const float du = dinv[u];
    float ax = 0.f, ay = 0.f;
    for (int j0 = 0; j0 < d; j0 += 64) {
        int v = 0;
        float dv = 0.f;
        if (j0 + lane < d) {
            v = adj[start + j0 + lane];
            dv = dinv[v];
        }
        const int cnt = min(64, d - j0);
        for (int jj = 0; jj < cnt; ++jj) {
            int vv = __shfl(v, jj);
            float w = du * __shfl(dv, jj);
            const float2 m = *(const float2*)(xw + (size_t)vv * C + 2 * lane);
            ax = fmaf(w, m.x, ax);
            ay = fmaf(w, m.y, ay);
        }
    }
    float2* op = (float2*)(out + (size_t)u * C + 2 * lane);
    float2 o = *op;
    o.x += ax;
    o.y += ay;
    *op = o;
}

// ---------------------------------------------------------------- launch ---
extern "C" void kernel_launch(void* const* d_in, const int* in_sizes, int n_in,
                              void* d_out, int out_size, void* d_ws, size_t ws_size,
                              hipStream_t stream) {
    const float* x  = (const float*)d_in[0];
    const float* W  = (const float*)d_in[1];
    const float* b  = (const float*)d_in[2];
    const int*   ei = (const int*)d_in[3];
    float* out = (float*)d_out;

    // workspace layout: xw [N*C f32] | deg [N i32] | dinv [N f32]
    //                   | rowptr [N+1 i32] | adj [2E i32]   (~65.2 MB)
    char* p = (char*)d_ws;
    float* xw = (float*)p;          p += (size_t)N * C * sizeof(float);
    int* deg = (int*)p;             p += (size_t)N * sizeof(int);
    float* dinv = (float*)p;        p += (size_t)N * sizeof(float);
    int* rowptr = (int*)p;          p += (size_t)(N + 4) * sizeof(int);
    int* adj = (int*)p;

    hipMemsetAsync(deg, 0, N * sizeof(int), stream);
    k_deg<<<(E + 255) / 256, 256, 0, stream>>>(ei, deg);
    k_dinv<<<(N + 255) / 256, 256, 0, stream>>>(deg, dinv);
    k_scan<<<1, 1024, 0, stream>>>(deg, rowptr);
    k_fill<<<(E + 255) / 256, 256, 0, stream>>>(ei, rowptr, adj);
    k_gemm<<<(N + 63) / 64, 256, 0, stream>>>(x, W, b, dinv, xw, out);
    k_gather<<<(N + 3) / 4, 256, 0, stream>>>(rowptr, deg, dinv, adj, xw, out);
}

// Round 3
// 746.727 us; speedup vs baseline: 3.8234x; 1.3258x over previous
//
#include <hip/hip_runtime.h>
#include <math.h>

constexpr int N = 100000;
constexpr int E = 1600000;
constexpr int C = 128;
constexpr int NODES_PER_GROUP = (N + 7) / 8;  // 12500, XCD-partitioned fill

__device__ inline unsigned f2bf(float f) {   // fp32 -> bf16 bits, RNE
    unsigned u = __float_as_uint(f);
    return (u + 0x7fffu + ((u >> 16) & 1u)) >> 16;
}
__device__ inline unsigned pack2(float lo, float hi) {
    return f2bf(lo) | (f2bf(hi) << 16);
}
__device__ inline float bf_lo(unsigned m) { return __uint_as_float(m << 16); }
__device__ inline float bf_hi(unsigned m) { return __uint_as_float(m & 0xffff0000u); }

// ---------------------------------------------------------------- degree ---
__global__ __launch_bounds__(256) void k_deg(const int* __restrict__ ei,
                                             int* __restrict__ deg) {
    int e = blockIdx.x * 256 + threadIdx.x;
    if (e < E) {
        atomicAdd(&deg[ei[e]], 1);
        atomicAdd(&deg[ei[E + e]], 1);
    }
}

__global__ __launch_bounds__(256) void k_dinv(const int* __restrict__ deg,
                                              float* __restrict__ dinv) {
    int n = blockIdx.x * 256 + threadIdx.x;
    if (n < N) dinv[n] = rsqrtf((float)deg[n] + 1.0f);
}

// ------------------------------------------------------- exclusive scan ----
__global__ __launch_bounds__(1024) void k_scan(const int* __restrict__ deg,
                                               int* __restrict__ rowptr) {
    __shared__ int part[1024];
    const int t = threadIdx.x;
    const int CH = (N + 1023) >> 10;  // 98
    const int base = t * CH;
    int s = 0;
    for (int i = 0; i < CH; ++i) {
        int idx = base + i;
        if (idx < N) s += deg[idx];
    }
    part[t] = s;
    __syncthreads();
    for (int off = 1; off < 1024; off <<= 1) {
        int add = (t >= off) ? part[t - off] : 0;
        __syncthreads();
        part[t] += add;
        __syncthreads();
    }
    int run = (t == 0) ? 0 : part[t - 1];
    for (int i = 0; i < CH; ++i) {
        int idx = base + i;
        if (idx < N) { rowptr[idx] = run; run += deg[idx]; }
    }
}

// ------------------------------------------------------------- CSR fill ----
// XCD-partitioned: group g = blockIdx&7 owns dest nodes [g*12500,(g+1)*12500).
// Each group streams the whole edge list (L3-resident) but writes only its
// own 1.6 MB adj slice -> slice stays resident in that XCD's L2, lines fill
// completely before eviction (kills the 16x partial-line write amplification).
// Correct regardless of actual block->XCD mapping.
__global__ __launch_bounds__(256) void k_fill(const int* __restrict__ ei,
                                              int* __restrict__ cursor,
                                              int* __restrict__ adj) {
    const int g  = blockIdx.x & 7;
    const int lb = blockIdx.x >> 3;       // local block within group
    const int nb = gridDim.x >> 3;        // blocks per group
    const int lo = g * NODES_PER_GROUP;
    const int hi = min(N, lo + NODES_PER_GROUP);
    for (int e = lb * 256 + threadIdx.x; e < E; e += nb * 256) {
        int u = ei[e], v = ei[E + e];
        if (u >= lo && u < hi) adj[atomicAdd(&cursor[u], 1)] = v;
        if (v >= lo && v < hi) adj[atomicAdd(&cursor[v], 1)] = u;
    }
}

// ------------------------------------------------------------------ GEMM ---
// acc = x @ W ; writes xw16 (packed bf16 pairs) for the gather, and
// out = dinv^2 * acc + b (self-loop + bias, fp32 precise).
__global__ __launch_bounds__(256) void k_gemm(const float* __restrict__ x,
                                              const float* __restrict__ W,
                                              const float* __restrict__ b,
                                              const float* __restrict__ dinv,
                                              unsigned* __restrict__ xw16,
                                              float* __restrict__ out) {
    __shared__ float Ws[32][128];   // 16 KB
    __shared__ float xs[64][33];    // pad +1: breaks bank conflicts

    const int t   = threadIdx.x;
    const int r0  = (t & 15) * 4;   // 4 rows per thread
    const int c0  = (t >> 4) * 8;   // 8 cols per thread
    const int bid = blockIdx.x;

    float acc[4][8];
#pragma unroll
    for (int i = 0; i < 4; ++i)
#pragma unroll
        for (int j = 0; j < 8; ++j) acc[i][j] = 0.0f;

    const int lrow = t >> 2;
    const int lk   = (t & 3) * 8;
    const long grow = (long)bid * 64 + lrow;
    const bool rvalid = grow < N;

    for (int k0 = 0; k0 < C; k0 += 32) {
        const float4* Wg = (const float4*)(W + (size_t)k0 * C);
        float4* Wsv = (float4*)(&Ws[0][0]);
#pragma unroll
        for (int j = 0; j < 4; ++j) Wsv[t + 256 * j] = Wg[t + 256 * j];
        float4 a0 = {0, 0, 0, 0}, a1 = {0, 0, 0, 0};
        if (rvalid) {
            a0 = *(const float4*)(x + grow * C + k0 + lk);
            a1 = *(const float4*)(x + grow * C + k0 + lk + 4);
        }
        xs[lrow][lk + 0] = a0.x; xs[lrow][lk + 1] = a0.y;
        xs[lrow][lk + 2] = a0.z; xs[lrow][lk + 3] = a0.w;
        xs[lrow][lk + 4] = a1.x; xs[lrow][lk + 5] = a1.y;
        xs[lrow][lk + 6] = a1.z; xs[lrow][lk + 7] = a1.w;
        __syncthreads();

#pragma unroll 8
        for (int k = 0; k < 32; ++k) {
            float4 w0 = *(const float4*)&Ws[k][c0];
            float4 w1 = *(const float4*)&Ws[k][c0 + 4];
            float xv[4];
#pragma unroll
            for (int i = 0; i < 4; ++i) xv[i] = xs[r0 + i][k];
#pragma unroll
            for (int i = 0; i < 4; ++i) {
                acc[i][0] = fmaf(xv[i], w0.x, acc[i][0]);
                acc[i][1] = fmaf(xv[i], w0.y, acc[i][1]);
                acc[i][2] = fmaf(xv[i], w0.z, acc[i][2]);
                acc[i][3] = fmaf(xv[i], w0.w, acc[i][3]);
                acc[i][4] = fmaf(xv[i], w1.x, acc[i][4]);
                acc[i][5] = fmaf(xv[i], w1.y, acc[i][5]);
                acc[i][6] = fmaf(xv[i], w1.z, acc[i][6]);
                acc[i][7] = fmaf(xv[i], w1.w, acc[i][7]);
            }
        }
        __syncthreads();
    }

    const float4 b0 = *(const float4*)(b + c0);
    const float4 b1 = *(const float4*)(b + c0 + 4);
#pragma unroll
    for (int i = 0; i < 4; ++i) {
        long r = (long)bid * 64 + r0 + i;
        if (r >= N) break;
        float s = dinv[r];
        s = s * s;
        float4 v0 = {acc[i][0], acc[i][1], acc[i][2], acc[i][3]};
        float4 v1 = {acc[i][4], acc[i][5], acc[i][6], acc[i][7]};
        uint4 pk = {pack2(v0.x, v0.y), pack2(v0.z, v0.w),
                    pack2(v1.x, v1.y), pack2(v1.z, v1.w)};
        *(uint4*)(xw16 + r * (C / 2) + (c0 >> 1)) = pk;
        float4 o0 = {fmaf(s, v0.x, b0.x), fmaf(s, v0.y, b0.y),
                     fmaf(s, v0.z, b0.z), fmaf(s, v0.w, b0.w)};
        float4 o1 = {fmaf(s, v1.x, b1.x), fmaf(s, v1.y, b1.y),
                     fmaf(s, v1.z, b1.z), fmaf(s, v1.w, b1.w)};
        *(float4*)(out + r * C + c0)     = o0;
        *(float4*)(out + r * C + c0 + 4) = o1;
    }
}

// ---------------------------------------------------------------- gather ---
// One wave per node; lane handles channels 2*lane, 2*lane+1 (one packed uint
// per neighbor row -> 256 B coalesced per gather). fp32 accumulate.
__global__ __launch_bounds__(256) void k_gather(const int* __restrict__ rowend,
                                                const int* __restrict__ deg,
                                                const float* __restrict__ dinv,
                                                const int* __restrict__ adj,
                                                const unsigned* __restrict__ xw16,
                                                float* __restrict__ out) {
    int u = blockIdx.x * 4 + (threadIdx.x >> 6);
    if (u >= N) return;
    const int lane = threadIdx.x & 63;
    const int d = deg[u];
    if (d == 0) return;
    const int start = rowend[u] - d;
    const float du = dinv[u];
    float ax = 0.f, ay = 0.f;
    for (int j0 = 0; j0 < d; j0 += 64) {
        int v = 0;
        float dv = 0.f;
        if (j0 + lane < d) {
            v = adj[start + j0 + lane];
            dv = dinv[v];
        }
        const int cnt = min(64, d - j0);
        int jj = 0;
        for (; jj + 2 <= cnt; jj += 2) {
            int v0 = __shfl(v, jj);
            int v1 = __shfl(v, jj + 1);
            float w0 = du * __shfl(dv, jj);
            float w1 = du * __shfl(dv, jj + 1);
            unsigned m0 = xw16[(size_t)v0 * (C / 2) + lane];
            unsigned m1 = xw16[(size_t)v1 * (C / 2) + lane];
            ax = fmaf(w0, bf_lo(m0), ax);
            ay = fmaf(w0, bf_hi(m0), ay);
            ax = fmaf(w1, bf_lo(m1), ax);
            ay = fmaf(w1, bf_hi(m1), ay);
        }
        if (jj < cnt) {
            int v0 = __shfl(v, jj);
            float w0 = du * __shfl(dv, jj);
            unsigned m0 = xw16[(size_t)v0 * (C / 2) + lane];
            ax = fmaf(w0, bf_lo(m0), ax);
            ay = fmaf(w0, bf_hi(m0), ay);
        }
    }
    float2* op = (float2*)(out + (size_t)u * C + 2 * lane);
    float2 o = *op;
    o.x += ax;
    o.y += ay;
    *op = o;
}

// ---------------------------------------------------------------- launch ---
extern "C" void kernel_launch(void* const* d_in, const int* in_sizes, int n_in,
                              void* d_out, int out_size, void* d_ws, size_t ws_size,
                              hipStream_t stream) {
    const float* x  = (const float*)d_in[0];
    const float* W  = (const float*)d_in[1];
    const float* b  = (const float*)d_in[2];
    const int*   ei = (const int*)d_in[3];
    float* out = (float*)d_out;

    // workspace: xw16 [N*64 u32] | deg [N] | dinv [N] | rowptr [N+4] | adj [2E]
    char* p = (char*)d_ws;
    unsigned* xw16 = (unsigned*)p;  p += (size_t)N * (C / 2) * sizeof(unsigned);
    int* deg = (int*)p;             p += (size_t)N * sizeof(int);
    float* dinv = (float*)p;        p += (size_t)N * sizeof(float);
    int* rowptr = (int*)p;          p += (size_t)(N + 4) * sizeof(int);
    int* adj = (int*)p;

    hipMemsetAsync(deg, 0, N * sizeof(int), stream);
    k_deg<<<(E + 255) / 256, 256, 0, stream>>>(ei, deg);
    k_dinv<<<(N + 255) / 256, 256, 0, stream>>>(deg, dinv);
    k_scan<<<1, 1024, 0, stream>>>(deg, rowptr);
    k_fill<<<640, 256, 0, stream>>>(ei, rowptr, adj);
    k_gemm<<<(N + 63) / 64, 256, 0, stream>>>(x, W, b, dinv, xw16, out);
    k_gather<<<(N + 3) / 4, 256, 0, stream>>>(rowptr, deg, dinv, adj, xw16, out);
}

// Round 4
// 563.617 us; speedup vs baseline: 5.0655x; 1.3249x over previous
//
#include <hip/hip_runtime.h>
#include <math.h>

constexpr int N = 100000;
constexpr int E = 1600000;
constexpr int C = 128;
constexpr int NODES_PER_GROUP = (N + 7) / 8;   // 12500, XCD-partitioned fill
constexpr int NBLK = (N + 255) / 256;          // 391 scan blocks

__device__ inline unsigned f2bf(float f) {   // fp32 -> bf16 bits, RNE
    unsigned u = __float_as_uint(f);
    return (u + 0x7fffu + ((u >> 16) & 1u)) >> 16;
}
__device__ inline unsigned pack2(float lo, float hi) {
    return f2bf(lo) | (f2bf(hi) << 16);
}
__device__ inline float bf_lo(unsigned m) { return __uint_as_float(m << 16); }
__device__ inline float bf_hi(unsigned m) { return __uint_as_float(m & 0xffff0000u); }

// ---------------------------------------------------------------- degree ---
__global__ __launch_bounds__(256) void k_deg(const int* __restrict__ ei,
                                             int* __restrict__ deg) {
    int e = blockIdx.x * 256 + threadIdx.x;
    if (e < E) {
        atomicAdd(&deg[ei[e]], 1);
        atomicAdd(&deg[ei[E + e]], 1);
    }
}

__global__ __launch_bounds__(256) void k_dinv(const int* __restrict__ deg,
                                              float* __restrict__ dinv) {
    int n = blockIdx.x * 256 + threadIdx.x;
    if (n < N) dinv[n] = rsqrtf((float)deg[n] + 1.0f);
}

// ----------------------------------------------- parallel 3-phase scan -----
// Phase 1: per-block sums of deg.
__global__ __launch_bounds__(256) void k_part(const int* __restrict__ deg,
                                              int* __restrict__ part) {
    __shared__ int red[4];
    int idx = blockIdx.x * 256 + threadIdx.x;
    int v = (idx < N) ? deg[idx] : 0;
#pragma unroll
    for (int off = 32; off; off >>= 1) v += __shfl_down(v, off);
    if ((threadIdx.x & 63) == 0) red[threadIdx.x >> 6] = v;
    __syncthreads();
    if (threadIdx.x == 0)
        part[blockIdx.x] = red[0] + red[1] + red[2] + red[3];
}

// Phase 2: exclusive scan of NBLK partials (single small block).
__global__ __launch_bounds__(512) void k_scan_part(int* __restrict__ part) {
    __shared__ int s[512];
    int t = threadIdx.x;
    int v = (t < NBLK) ? part[t] : 0;
    s[t] = v;
    __syncthreads();
#pragma unroll
    for (int off = 1; off < 512; off <<= 1) {
        int add = (t >= off) ? s[t - off] : 0;
        __syncthreads();
        s[t] += add;
        __syncthreads();
    }
    if (t < NBLK) part[t] = s[t] - v;   // exclusive
}

// Phase 3: block-local exclusive scan + partial offset -> rowptr.
__global__ __launch_bounds__(256) void k_rowptr(const int* __restrict__ deg,
                                                const int* __restrict__ part,
                                                int* __restrict__ rowptr) {
    __shared__ int s[256];
    int t = threadIdx.x;
    int idx = blockIdx.x * 256 + t;
    int v = (idx < N) ? deg[idx] : 0;
    s[t] = v;
    __syncthreads();
#pragma unroll
    for (int off = 1; off < 256; off <<= 1) {
        int add = (t >= off) ? s[t - off] : 0;
        __syncthreads();
        s[t] += add;
        __syncthreads();
    }
    if (idx < N) rowptr[idx] = part[blockIdx.x] + s[t] - v;
}

// ------------------------------------------------------------- CSR fill ----
// XCD-partitioned: group g = blockIdx&7 owns dest nodes [g*12500,(g+1)*12500).
// Each group streams the whole edge list (L3-resident) but writes only its
// own 1.6 MB adj slice -> stays in that XCD's L2, lines fill before eviction.
__global__ __launch_bounds__(256) void k_fill(const int* __restrict__ ei,
                                              int* __restrict__ cursor,
                                              int* __restrict__ adj) {
    const int g  = blockIdx.x & 7;
    const int lb = blockIdx.x >> 3;
    const int nb = gridDim.x >> 3;
    const int lo = g * NODES_PER_GROUP;
    const int hi = min(N, lo + NODES_PER_GROUP);
    for (int e = lb * 256 + threadIdx.x; e < E; e += nb * 256) {
        int u = ei[e], v = ei[E + e];
        if (u >= lo && u < hi) adj[atomicAdd(&cursor[u], 1)] = v;
        if (v >= lo && v < hi) adj[atomicAdd(&cursor[v], 1)] = u;
    }
}

// ------------------------------------------------------------------ GEMM ---
// acc = x @ W ; writes xw16 (packed bf16 pairs) for the gather, and
// out = dinv^2 * acc + b (self-loop + bias, fp32 precise).
__global__ __launch_bounds__(256) void k_gemm(const float* __restrict__ x,
                                              const float* __restrict__ W,
                                              const float* __restrict__ b,
                                              const float* __restrict__ dinv,
                                              unsigned* __restrict__ xw16,
                                              float* __restrict__ out) {
    __shared__ float Ws[32][128];
    __shared__ float xs[64][33];

    const int t   = threadIdx.x;
    const int r0  = (t & 15) * 4;
    const int c0  = (t >> 4) * 8;
    const int bid = blockIdx.x;

    float acc[4][8];
#pragma unroll
    for (int i = 0; i < 4; ++i)
#pragma unroll
        for (int j = 0; j < 8; ++j) acc[i][j] = 0.0f;

    const int lrow = t >> 2;
    const int lk   = (t & 3) * 8;
    const long grow = (long)bid * 64 + lrow;
    const bool rvalid = grow < N;

    for (int k0 = 0; k0 < C; k0 += 32) {
        const float4* Wg = (const float4*)(W + (size_t)k0 * C);
        float4* Wsv = (float4*)(&Ws[0][0]);
#pragma unroll
        for (int j = 0; j < 4; ++j) Wsv[t + 256 * j] = Wg[t + 256 * j];
        float4 a0 = {0, 0, 0, 0}, a1 = {0, 0, 0, 0};
        if (rvalid) {
            a0 = *(const float4*)(x + grow * C + k0 + lk);
            a1 = *(const float4*)(x + grow * C + k0 + lk + 4);
        }
        xs[lrow][lk + 0] = a0.x; xs[lrow][lk + 1] = a0.y;
        xs[lrow][lk + 2] = a0.z; xs[lrow][lk + 3] = a0.w;
        xs[lrow][lk + 4] = a1.x; xs[lrow][lk + 5] = a1.y;
        xs[lrow][lk + 6] = a1.z; xs[lrow][lk + 7] = a1.w;
        __syncthreads();

#pragma unroll 8
        for (int k = 0; k < 32; ++k) {
            float4 w0 = *(const float4*)&Ws[k][c0];
            float4 w1 = *(const float4*)&Ws[k][c0 + 4];
            float xv[4];
#pragma unroll
            for (int i = 0; i < 4; ++i) xv[i] = xs[r0 + i][k];
#pragma unroll
            for (int i = 0; i < 4; ++i) {
                acc[i][0] = fmaf(xv[i], w0.x, acc[i][0]);
                acc[i][1] = fmaf(xv[i], w0.y, acc[i][1]);
                acc[i][2] = fmaf(xv[i], w0.z, acc[i][2]);
                acc[i][3] = fmaf(xv[i], w0.w, acc[i][3]);
                acc[i][4] = fmaf(xv[i], w1.x, acc[i][4]);
                acc[i][5] = fmaf(xv[i], w1.y, acc[i][5]);
                acc[i][6] = fmaf(xv[i], w1.z, acc[i][6]);
                acc[i][7] = fmaf(xv[i], w1.w, acc[i][7]);
            }
        }
        __syncthreads();
    }

    const float4 b0 = *(const float4*)(b + c0);
    const float4 b1 = *(const float4*)(b + c0 + 4);
#pragma unroll
    for (int i = 0; i < 4; ++i) {
        long r = (long)bid * 64 + r0 + i;
        if (r >= N) break;
        float s = dinv[r];
        s = s * s;
        float4 v0 = {acc[i][0], acc[i][1], acc[i][2], acc[i][3]};
        float4 v1 = {acc[i][4], acc[i][5], acc[i][6], acc[i][7]};
        uint4 pk = {pack2(v0.x, v0.y), pack2(v0.z, v0.w),
                    pack2(v1.x, v1.y), pack2(v1.z, v1.w)};
        *(uint4*)(xw16 + r * (C / 2) + (c0 >> 1)) = pk;
        float4 o0 = {fmaf(s, v0.x, b0.x), fmaf(s, v0.y, b0.y),
                     fmaf(s, v0.z, b0.z), fmaf(s, v0.w, b0.w)};
        float4 o1 = {fmaf(s, v1.x, b1.x), fmaf(s, v1.y, b1.y),
                     fmaf(s, v1.z, b1.z), fmaf(s, v1.w, b1.w)};
        *(float4*)(out + r * C + c0)     = o0;
        *(float4*)(out + r * C + c0 + 4) = o1;
    }
}

// ---------------------------------------------------------------- gather ---
// One wave per node; lane handles channels 2*lane, 2*lane+1 (one packed uint
// per neighbor row -> 256 B coalesced per gather). fp32 accumulate.
__global__ __launch_bounds__(256) void k_gather(const int* __restrict__ rowend,
                                                const int* __restrict__ deg,
                                                const float* __restrict__ dinv,
                                                const int* __restrict__ adj,
                                                const unsigned* __restrict__ xw16,
                                                float* __restrict__ out) {
    int u = blockIdx.x * 4 + (threadIdx.x >> 6);
    if (u >= N) return;
    const int lane = threadIdx.x & 63;
    const int d = deg[u];
    if (d == 0) return;
    const int start = rowend[u] - d;
    const float du = dinv[u];
    float ax = 0.f, ay = 0.f;
    for (int j0 = 0; j0 < d; j0 += 64) {
        int v = 0;
        float dv = 0.f;
        if (j0 + lane < d) {
            v = adj[start + j0 + lane];
            dv = dinv[v];
        }
        const int cnt = min(64, d - j0);
        int jj = 0;
        for (; jj + 2 <= cnt; jj += 2) {
            int v0 = __shfl(v, jj);
            int v1 = __shfl(v, jj + 1);
            float w0 = du * __shfl(dv, jj);
            float w1 = du * __shfl(dv, jj + 1);
            unsigned m0 = xw16[(size_t)v0 * (C / 2) + lane];
            unsigned m1 = xw16[(size_t)v1 * (C / 2) + lane];
            ax = fmaf(w0, bf_lo(m0), ax);
            ay = fmaf(w0, bf_hi(m0), ay);
            ax = fmaf(w1, bf_lo(m1), ax);
            ay = fmaf(w1, bf_hi(m1), ay);
        }
        if (jj < cnt) {
            int v0 = __shfl(v, jj);
            float w0 = du * __shfl(dv, jj);
            unsigned m0 = xw16[(size_t)v0 * (C / 2) + lane];
            ax = fmaf(w0, bf_lo(m0), ax);
            ay = fmaf(w0, bf_hi(m0), ay);
        }
    }
    float2* op = (float2*)(out + (size_t)u * C + 2 * lane);
    float2 o = *op;
    o.x += ax;
    o.y += ay;
    *op = o;
}

// ---------------------------------------------------------------- launch ---
extern "C" void kernel_launch(void* const* d_in, const int* in_sizes, int n_in,
                              void* d_out, int out_size, void* d_ws, size_t ws_size,
                              hipStream_t stream) {
    const float* x  = (const float*)d_in[0];
    const float* W  = (const float*)d_in[1];
    const float* b  = (const float*)d_in[2];
    const int*   ei = (const int*)d_in[3];
    float* out = (float*)d_out;

    // workspace: xw16 [N*64 u32] | deg [N] | dinv [N] | rowptr [N+4] |
    //            part [512] | adj [2E]
    char* p = (char*)d_ws;
    unsigned* xw16 = (unsigned*)p;  p += (size_t)N * (C / 2) * sizeof(unsigned);
    int* deg = (int*)p;             p += (size_t)N * sizeof(int);
    float* dinv = (float*)p;        p += (size_t)N * sizeof(float);
    int* rowptr = (int*)p;          p += (size_t)(N + 4) * sizeof(int);
    int* part = (int*)p;            p += 512 * sizeof(int);
    int* adj = (int*)p;

    hipMemsetAsync(deg, 0, N * sizeof(int), stream);
    k_deg<<<(E + 255) / 256, 256, 0, stream>>>(ei, deg);
    k_dinv<<<(N + 255) / 256, 256, 0, stream>>>(deg, dinv);
    k_part<<<NBLK, 256, 0, stream>>>(deg, part);
    k_scan_part<<<1, 512, 0, stream>>>(part);
    k_rowptr<<<NBLK, 256, 0, stream>>>(deg, part, rowptr);
    k_fill<<<640, 256, 0, stream>>>(ei, rowptr, adj);
    k_gemm<<<(N + 63) / 64, 256, 0, stream>>>(x, W, b, dinv, xw16, out);
    k_gather<<<(N + 3) / 4, 256, 0, stream>>>(rowptr, deg, dinv, adj, xw16, out);
}

// Round 5
// 536.712 us; speedup vs baseline: 5.3195x; 1.0501x over previous
//
#include <hip/hip_runtime.h>
#include <math.h>

constexpr int N = 100000;
constexpr int E = 1600000;
constexpr int C = 128;
constexpr int NODES_PER_GROUP = (N + 7) / 8;   // 12500, XCD-partitioned fill
constexpr int NBLK = (N + 255) / 256;          // 391 scan blocks

__device__ inline unsigned f2bf(float f) {   // fp32 -> bf16 bits, RNE
    unsigned u = __float_as_uint(f);
    return (u + 0x7fffu + ((u >> 16) & 1u)) >> 16;
}
__device__ inline unsigned pack2(float lo, float hi) {
    return f2bf(lo) | (f2bf(hi) << 16);
}
__device__ inline float bf_lo(unsigned m) { return __uint_as_float(m << 16); }
__device__ inline float bf_hi(unsigned m) { return __uint_as_float(m & 0xffff0000u); }

// ---------------------------------------------------------------- degree ---
// NT loads: don't let the 12.8 MB edge stream evict the hot 400 KB deg region.
__global__ __launch_bounds__(256) void k_deg(const int* __restrict__ ei,
                                             int* __restrict__ deg) {
    int e = blockIdx.x * 256 + threadIdx.x;
    if (e < E) {
        int u = __builtin_nontemporal_load(ei + e);
        int v = __builtin_nontemporal_load(ei + E + e);
        atomicAdd(&deg[u], 1);
        atomicAdd(&deg[v], 1);
    }
}

// ----------------------------------------------- parallel 3-phase scan -----
// Phase 1: per-block sums of deg; dinv fused in (same pass over deg).
__global__ __launch_bounds__(256) void k_part(const int* __restrict__ deg,
                                              float* __restrict__ dinv,
                                              int* __restrict__ part) {
    __shared__ int red[4];
    int idx = blockIdx.x * 256 + threadIdx.x;
    int v = (idx < N) ? deg[idx] : 0;
    if (idx < N) dinv[idx] = rsqrtf((float)v + 1.0f);
#pragma unroll
    for (int off = 32; off; off >>= 1) v += __shfl_down(v, off);
    if ((threadIdx.x & 63) == 0) red[threadIdx.x >> 6] = v;
    __syncthreads();
    if (threadIdx.x == 0)
        part[blockIdx.x] = red[0] + red[1] + red[2] + red[3];
}

// Phase 2: exclusive scan of NBLK partials (single small block).
__global__ __launch_bounds__(512) void k_scan_part(int* __restrict__ part) {
    __shared__ int s[512];
    int t = threadIdx.x;
    int v = (t < NBLK) ? part[t] : 0;
    s[t] = v;
    __syncthreads();
#pragma unroll
    for (int off = 1; off < 512; off <<= 1) {
        int add = (t >= off) ? s[t - off] : 0;
        __syncthreads();
        s[t] += add;
        __syncthreads();
    }
    if (t < NBLK) part[t] = s[t] - v;   // exclusive
}

// Phase 3: block-local exclusive scan + partial offset -> rowptr.
__global__ __launch_bounds__(256) void k_rowptr(const int* __restrict__ deg,
                                                const int* __restrict__ part,
                                                int* __restrict__ rowptr) {
    __shared__ int s[256];
    int t = threadIdx.x;
    int idx = blockIdx.x * 256 + t;
    int v = (idx < N) ? deg[idx] : 0;
    s[t] = v;
    __syncthreads();
#pragma unroll
    for (int off = 1; off < 256; off <<= 1) {
        int add = (t >= off) ? s[t - off] : 0;
        __syncthreads();
        s[t] += add;
        __syncthreads();
    }
    if (idx < N) rowptr[idx] = part[blockIdx.x] + s[t] - v;
}

// ------------------------------------------------------------- CSR fill ----
// XCD-partitioned (group g = blockIdx&7 owns dest nodes [g*12500,(g+1)*12500))
// + NT edge loads so the stream doesn't evict the dirty adj/cursor lines.
__global__ __launch_bounds__(256) void k_fill(const int* __restrict__ ei,
                                              int* __restrict__ cursor,
                                              int* __restrict__ adj) {
    const int g  = blockIdx.x & 7;
    const int lb = blockIdx.x >> 3;
    const int nb = gridDim.x >> 3;
    const int lo = g * NODES_PER_GROUP;
    const int hi = min(N, lo + NODES_PER_GROUP);
    for (int e = lb * 256 + threadIdx.x; e < E; e += nb * 256) {
        int u = __builtin_nontemporal_load(ei + e);
        int v = __builtin_nontemporal_load(ei + E + e);
        if (u >= lo && u < hi) adj[atomicAdd(&cursor[u], 1)] = v;
        if (v >= lo && v < hi) adj[atomicAdd(&cursor[v], 1)] = u;
    }
}

// ------------------------------------------------------------------ GEMM ---
// xw16 = bf16(x @ W). Self-loop/bias moved to the gather; no fp32 out here.
__global__ __launch_bounds__(256) void k_gemm(const float* __restrict__ x,
                                              const float* __restrict__ W,
                                              unsigned* __restrict__ xw16) {
    __shared__ float Ws[32][128];
    __shared__ float xs[64][33];

    const int t   = threadIdx.x;
    const int r0  = (t & 15) * 4;
    const int c0  = (t >> 4) * 8;
    const int bid = blockIdx.x;

    float acc[4][8];
#pragma unroll
    for (int i = 0; i < 4; ++i)
#pragma unroll
        for (int j = 0; j < 8; ++j) acc[i][j] = 0.0f;

    const int lrow = t >> 2;
    const int lk   = (t & 3) * 8;
    const long grow = (long)bid * 64 + lrow;
    const bool rvalid = grow < N;

    for (int k0 = 0; k0 < C; k0 += 32) {
        const float4* Wg = (const float4*)(W + (size_t)k0 * C);
        float4* Wsv = (float4*)(&Ws[0][0]);
#pragma unroll
        for (int j = 0; j < 4; ++j) Wsv[t + 256 * j] = Wg[t + 256 * j];
        float4 a0 = {0, 0, 0, 0}, a1 = {0, 0, 0, 0};
        if (rvalid) {
            a0 = *(const float4*)(x + grow * C + k0 + lk);
            a1 = *(const float4*)(x + grow * C + k0 + lk + 4);
        }
        xs[lrow][lk + 0] = a0.x; xs[lrow][lk + 1] = a0.y;
        xs[lrow][lk + 2] = a0.z; xs[lrow][lk + 3] = a0.w;
        xs[lrow][lk + 4] = a1.x; xs[lrow][lk + 5] = a1.y;
        xs[lrow][lk + 6] = a1.z; xs[lrow][lk + 7] = a1.w;
        __syncthreads();

#pragma unroll 8
        for (int k = 0; k < 32; ++k) {
            float4 w0 = *(const float4*)&Ws[k][c0];
            float4 w1 = *(const float4*)&Ws[k][c0 + 4];
            float xv[4];
#pragma unroll
            for (int i = 0; i < 4; ++i) xv[i] = xs[r0 + i][k];
#pragma unroll
            for (int i = 0; i < 4; ++i) {
                acc[i][0] = fmaf(xv[i], w0.x, acc[i][0]);
                acc[i][1] = fmaf(xv[i], w0.y, acc[i][1]);
                acc[i][2] = fmaf(xv[i], w0.z, acc[i][2]);
                acc[i][3] = fmaf(xv[i], w0.w, acc[i][3]);
                acc[i][4] = fmaf(xv[i], w1.x, acc[i][4]);
                acc[i][5] = fmaf(xv[i], w1.y, acc[i][5]);
                acc[i][6] = fmaf(xv[i], w1.z, acc[i][6]);
                acc[i][7] = fmaf(xv[i], w1.w, acc[i][7]);
            }
        }
        __syncthreads();
    }

#pragma unroll
    for (int i = 0; i < 4; ++i) {
        long r = (long)bid * 64 + r0 + i;
        if (r >= N) break;
        uint4 pk = {pack2(acc[i][0], acc[i][1]), pack2(acc[i][2], acc[i][3]),
                    pack2(acc[i][4], acc[i][5]), pack2(acc[i][6], acc[i][7])};
        *(uint4*)(xw16 + r * (C / 2) + (c0 >> 1)) = pk;
    }
}

// ---------------------------------------------------------------- gather ---
// One wave per node; lane owns channels 2*lane, 2*lane+1. Self-loop + bias
// fused (out written once, never read). 4x unroll for memory-level parallelism.
__global__ __launch_bounds__(256) void k_gather(const int* __restrict__ rowend,
                                                const int* __restrict__ deg,
                                                const float* __restrict__ dinv,
                                                const int* __restrict__ adj,
                                                const unsigned* __restrict__ xw16,
                                                const float* __restrict__ b,
                                                float* __restrict__ out) {
    int u = blockIdx.x * 4 + (threadIdx.x >> 6);
    if (u >= N) return;
    const int lane = threadIdx.x & 63;
    const int d = deg[u];
    const int start = rowend[u] - d;
    const float du = dinv[u];
    // self-loop + bias
    const unsigned ms = xw16[(size_t)u * (C / 2) + lane];
    const float2 bb = *(const float2*)(b + 2 * lane);
    const float s2 = du * du;
    float ax = fmaf(s2, bf_lo(ms), bb.x);
    float ay = fmaf(s2, bf_hi(ms), bb.y);

    for (int j0 = 0; j0 < d; j0 += 64) {
        int v = 0;
        float dv = 0.f;
        if (j0 + lane < d) {
            v = adj[start + j0 + lane];
            dv = dinv[v];
        }
        const int cnt = min(64, d - j0);
        int jj = 0;
        for (; jj + 4 <= cnt; jj += 4) {
            int v0 = __shfl(v, jj),     v1 = __shfl(v, jj + 1);
            int v2 = __shfl(v, jj + 2), v3 = __shfl(v, jj + 3);
            float w0 = du * __shfl(dv, jj),     w1 = du * __shfl(dv, jj + 1);
            float w2 = du * __shfl(dv, jj + 2), w3 = du * __shfl(dv, jj + 3);
            unsigned m0 = xw16[(size_t)v0 * (C / 2) + lane];
            unsigned m1 = xw16[(size_t)v1 * (C / 2) + lane];
            unsigned m2 = xw16[(size_t)v2 * (C / 2) + lane];
            unsigned m3 = xw16[(size_t)v3 * (C / 2) + lane];
            ax = fmaf(w0, bf_lo(m0), ax); ay = fmaf(w0, bf_hi(m0), ay);
            ax = fmaf(w1, bf_lo(m1), ax); ay = fmaf(w1, bf_hi(m1), ay);
            ax = fmaf(w2, bf_lo(m2), ax); ay = fmaf(w2, bf_hi(m2), ay);
            ax = fmaf(w3, bf_lo(m3), ax); ay = fmaf(w3, bf_hi(m3), ay);
        }
        for (; jj < cnt; ++jj) {
            int vv = __shfl(v, jj);
            float w = du * __shfl(dv, jj);
            unsigned m = xw16[(size_t)vv * (C / 2) + lane];
            ax = fmaf(w, bf_lo(m), ax);
            ay = fmaf(w, bf_hi(m), ay);
        }
    }
    float2 o = {ax, ay};
    *(float2*)(out + (size_t)u * C + 2 * lane) = o;
}

// ---------------------------------------------------------------- launch ---
extern "C" void kernel_launch(void* const* d_in, const int* in_sizes, int n_in,
                              void* d_out, int out_size, void* d_ws, size_t ws_size,
                              hipStream_t stream) {
    const float* x  = (const float*)d_in[0];
    const float* W  = (const float*)d_in[1];
    const float* b  = (const float*)d_in[2];
    const int*   ei = (const int*)d_in[3];
    float* out = (float*)d_out;

    // workspace: xw16 [N*64 u32] | deg [N] | dinv [N] | rowptr [N+4] |
    //            part [512] | adj [2E]
    char* p = (char*)d_ws;
    unsigned* xw16 = (unsigned*)p;  p += (size_t)N * (C / 2) * sizeof(unsigned);
    int* deg = (int*)p;             p += (size_t)N * sizeof(int);
    float* dinv = (float*)p;        p += (size_t)N * sizeof(float);
    int* rowptr = (int*)p;          p += (size_t)(N + 4) * sizeof(int);
    int* part = (int*)p;            p += 512 * sizeof(int);
    int* adj = (int*)p;

    hipMemsetAsync(deg, 0, N * sizeof(int), stream);
    k_deg<<<(E + 255) / 256, 256, 0, stream>>>(ei, deg);
    k_part<<<NBLK, 256, 0, stream>>>(deg, dinv, part);
    k_scan_part<<<1, 512, 0, stream>>>(part);
    k_rowptr<<<NBLK, 256, 0, stream>>>(deg, part, rowptr);
    k_fill<<<2048, 256, 0, stream>>>(ei, rowptr, adj);
    k_gemm<<<(N + 63) / 64, 256, 0, stream>>>(x, W, xw16);
    k_gather<<<(N + 3) / 4, 256, 0, stream>>>(rowptr, deg, dinv, adj, xw16, b, out);
}

// Round 6
// 518.672 us; speedup vs baseline: 5.5045x; 1.0348x over previous
//
#include <hip/hip_runtime.h>
#include <math.h>

constexpr int N = 100000;
constexpr int E = 1600000;
constexpr int C = 128;
constexpr int NBLK  = (N + 255) / 256;        // 391 scan blocks
constexpr int NBUCK = 64;                     // dest buckets for CSR build
constexpr int NPB   = (N + NBUCK - 1) / NBUCK;  // 1563 nodes per bucket
constexpr int CAP   = 53248;                  // staging cap/bucket (mean 50000, +14 sigma)

__device__ inline unsigned f2bf(float f) {   // fp32 -> bf16 bits, RNE
    unsigned u = __float_as_uint(f);
    return (u + 0x7fffu + ((u >> 16) & 1u)) >> 16;
}
__device__ inline unsigned pack2(float lo, float hi) {
    return f2bf(lo) | (f2bf(hi) << 16);
}
__device__ inline float bf_lo(unsigned m) { return __uint_as_float(m << 16); }
__device__ inline float bf_hi(unsigned m) { return __uint_as_float(m & 0xffff0000u); }

// ------------------------------------------------------ bin + degree pass --
// One pass over the edge list. Per 1024-edge tile: LDS-aggregated bucket
// counts -> one global atomic per bucket -> dense appends of (dest,src)
// into per-bucket staging (~256 B/bucket/tile: full-line writes). Also
// accumulates deg (replaces k_deg).
__global__ __launch_bounds__(256) void k_bin(const int* __restrict__ ei,
                                             int* __restrict__ deg,
                                             int* __restrict__ gcount,
                                             uint2* __restrict__ staging) {
    __shared__ int cnt[NBUCK];
    __shared__ int wbase[NBUCK];
    const int t = threadIdx.x;
    for (long tile = (long)blockIdx.x * 1024; tile < E;
         tile += (long)gridDim.x * 1024) {
        if (t < NBUCK) cnt[t] = 0;
        __syncthreads();
        int eu[4], ev[4], lo0[4], lo1[4];
        bool val[4];
#pragma unroll
        for (int j = 0; j < 4; ++j) {
            long e = tile + j * 256 + t;
            val[j] = e < E;
            if (val[j]) {
                int u = __builtin_nontemporal_load(ei + e);
                int v = __builtin_nontemporal_load(ei + E + e);
                eu[j] = u; ev[j] = v;
                atomicAdd(&deg[u], 1);
                atomicAdd(&deg[v], 1);
                lo0[j] = atomicAdd(&cnt[u / NPB], 1);
                lo1[j] = atomicAdd(&cnt[v / NPB], 1);
            }
        }
        __syncthreads();
        if (t < NBUCK) wbase[t] = atomicAdd(&gcount[t], cnt[t]);
        __syncthreads();
#pragma unroll
        for (int j = 0; j < 4; ++j) {
            if (val[j]) {
                int b0 = eu[j] / NPB, b1 = ev[j] / NPB;
                staging[(size_t)b0 * CAP + wbase[b0] + lo0[j]] =
                    make_uint2((unsigned)eu[j], (unsigned)ev[j]);
                staging[(size_t)b1 * CAP + wbase[b1] + lo1[j]] =
                    make_uint2((unsigned)ev[j], (unsigned)eu[j]);
            }
        }
        __syncthreads();
    }
}

// ----------------------------------------------- parallel 3-phase scan -----
__global__ __launch_bounds__(256) void k_part(const int* __restrict__ deg,
                                              float* __restrict__ dinv,
                                              int* __restrict__ part) {
    __shared__ int red[4];
    int idx = blockIdx.x * 256 + threadIdx.x;
    int v = (idx < N) ? deg[idx] : 0;
    if (idx < N) dinv[idx] = rsqrtf((float)v + 1.0f);
#pragma unroll
    for (int off = 32; off; off >>= 1) v += __shfl_down(v, off);
    if ((threadIdx.x & 63) == 0) red[threadIdx.x >> 6] = v;
    __syncthreads();
    if (threadIdx.x == 0)
        part[blockIdx.x] = red[0] + red[1] + red[2] + red[3];
}

__global__ __launch_bounds__(512) void k_scan_part(int* __restrict__ part) {
    __shared__ int s[512];
    int t = threadIdx.x;
    int v = (t < NBLK) ? part[t] : 0;
    s[t] = v;
    __syncthreads();
#pragma unroll
    for (int off = 1; off < 512; off <<= 1) {
        int add = (t >= off) ? s[t - off] : 0;
        __syncthreads();
        s[t] += add;
        __syncthreads();
    }
    if (t < NBLK) part[t] = s[t] - v;   // exclusive
}

__global__ __launch_bounds__(256) void k_rowptr(const int* __restrict__ deg,
                                                const int* __restrict__ part,
                                                int* __restrict__ rowptr) {
    __shared__ int s[256];
    int t = threadIdx.x;
    int idx = blockIdx.x * 256 + t;
    int v = (idx < N) ? deg[idx] : 0;
    s[t] = v;
    __syncthreads();
#pragma unroll
    for (int off = 1; off < 256; off <<= 1) {
        int add = (t >= off) ? s[t - off] : 0;
        __syncthreads();
        s[t] += add;
        __syncthreads();
    }
    if (idx < N) rowptr[idx] = part[blockIdx.x] + s[t] - v;
}

// ------------------------------------------------------------- CSR fill ----
// Bucket g: dense NT reads of its staged entries, scatter into its 200 KB
// adj slice (8 slices/XCD = 1.6 MB dirty footprint under any mapping).
// Destroys cursor (= rowptr copy): after this, cursor[u] = end of segment.
__global__ __launch_bounds__(256) void k_fill2(const uint2* __restrict__ staging,
                                               const int* __restrict__ gcount,
                                               int* __restrict__ cursor,
                                               int* __restrict__ adj) {
    const int g  = blockIdx.x & (NBUCK - 1);
    const int lb = blockIdx.x >> 6;
    const int nb = gridDim.x >> 6;
    const int cnt = gcount[g];
    const unsigned long long* base =
        (const unsigned long long*)(staging + (size_t)g * CAP);
    for (int i = lb * 256 + threadIdx.x; i < cnt; i += nb * 256) {
        unsigned long long e = __builtin_nontemporal_load(base + i);
        int dst = (int)(e & 0xffffffffu);
        int src = (int)(e >> 32);
        adj[atomicAdd(&cursor[dst], 1)] = src;
    }
}

// ------------------------------------------------------------------ GEMM ---
// xw16 = bf16(x @ W). Self-loop/bias handled in the gather.
__global__ __launch_bounds__(256) void k_gemm(const float* __restrict__ x,
                                              const float* __restrict__ W,
                                              unsigned* __restrict__ xw16) {
    __shared__ float Ws[32][128];
    __shared__ float xs[64][33];

    const int t   = threadIdx.x;
    const int r0  = (t & 15) * 4;
    const int c0  = (t >> 4) * 8;
    const int bid = blockIdx.x;

    float acc[4][8];
#pragma unroll
    for (int i = 0; i < 4; ++i)
#pragma unroll
        for (int j = 0; j < 8; ++j) acc[i][j] = 0.0f;

    const int lrow = t >> 2;
    const int lk   = (t & 3) * 8;
    const long grow = (long)bid * 64 + lrow;
    const bool rvalid = grow < N;

    for (int k0 = 0; k0 < C; k0 += 32) {
        const float4* Wg = (const float4*)(W + (size_t)k0 * C);
        float4* Wsv = (float4*)(&Ws[0][0]);
#pragma unroll
        for (int j = 0; j < 4; ++j) Wsv[t + 256 * j] = Wg[t + 256 * j];
        float4 a0 = {0, 0, 0, 0}, a1 = {0, 0, 0, 0};
        if (rvalid) {
            a0 = *(const float4*)(x + grow * C + k0 + lk);
            a1 = *(const float4*)(x + grow * C + k0 + lk + 4);
        }
        xs[lrow][lk + 0] = a0.x; xs[lrow][lk + 1] = a0.y;
        xs[lrow][lk + 2] = a0.z; xs[lrow][lk + 3] = a0.w;
        xs[lrow][lk + 4] = a1.x; xs[lrow][lk + 5] = a1.y;
        xs[lrow][lk + 6] = a1.z; xs[lrow][lk + 7] = a1.w;
        __syncthreads();

#pragma unroll 8
        for (int k = 0; k < 32; ++k) {
            float4 w0 = *(const float4*)&Ws[k][c0];
            float4 w1 = *(const float4*)&Ws[k][c0 + 4];
            float xv[4];
#pragma unroll
            for (int i = 0; i < 4; ++i) xv[i] = xs[r0 + i][k];
#pragma unroll
            for (int i = 0; i < 4; ++i) {
                acc[i][0] = fmaf(xv[i], w0.x, acc[i][0]);
                acc[i][1] = fmaf(xv[i], w0.y, acc[i][1]);
                acc[i][2] = fmaf(xv[i], w0.z, acc[i][2]);
                acc[i][3] = fmaf(xv[i], w0.w, acc[i][3]);
                acc[i][4] = fmaf(xv[i], w1.x, acc[i][4]);
                acc[i][5] = fmaf(xv[i], w1.y, acc[i][5]);
                acc[i][6] = fmaf(xv[i], w1.z, acc[i][6]);
                acc[i][7] = fmaf(xv[i], w1.w, acc[i][7]);
            }
        }
        __syncthreads();
    }

#pragma unroll
    for (int i = 0; i < 4; ++i) {
        long r = (long)bid * 64 + r0 + i;
        if (r >= N) break;
        uint4 pk = {pack2(acc[i][0], acc[i][1]), pack2(acc[i][2], acc[i][3]),
                    pack2(acc[i][4], acc[i][5]), pack2(acc[i][6], acc[i][7])};
        *(uint4*)(xw16 + r * (C / 2) + (c0 >> 1)) = pk;
    }
}

// ---------------------------------------------------------------- gather ---
__global__ __launch_bounds__(256) void k_gather(const int* __restrict__ rowend,
                                                const int* __restrict__ deg,
                                                const float* __restrict__ dinv,
                                                const int* __restrict__ adj,
                                                const unsigned* __restrict__ xw16,
                                                const float* __restrict__ b,
                                                float* __restrict__ out) {
    int u = blockIdx.x * 4 + (threadIdx.x >> 6);
    if (u >= N) return;
    const int lane = threadIdx.x & 63;
    const int d = deg[u];
    const int start = rowend[u] - d;
    const float du = dinv[u];
    // self-loop + bias
    const unsigned ms = xw16[(size_t)u * (C / 2) + lane];
    const float2 bb = *(const float2*)(b + 2 * lane);
    const float s2 = du * du;
    float ax = fmaf(s2, bf_lo(ms), bb.x);
    float ay = fmaf(s2, bf_hi(ms), bb.y);

    for (int j0 = 0; j0 < d; j0 += 64) {
        int v = 0;
        float dv = 0.f;
        if (j0 + lane < d) {
            v = adj[start + j0 + lane];
            dv = dinv[v];
        }
        const int cnt = min(64, d - j0);
        int jj = 0;
        for (; jj + 4 <= cnt; jj += 4) {
            int v0 = __shfl(v, jj),     v1 = __shfl(v, jj + 1);
            int v2 = __shfl(v, jj + 2), v3 = __shfl(v, jj + 3);
            float w0 = du * __shfl(dv, jj),     w1 = du * __shfl(dv, jj + 1);
            float w2 = du * __shfl(dv, jj + 2), w3 = du * __shfl(dv, jj + 3);
            unsigned m0 = xw16[(size_t)v0 * (C / 2) + lane];
            unsigned m1 = xw16[(size_t)v1 * (C / 2) + lane];
            unsigned m2 = xw16[(size_t)v2 * (C / 2) + lane];
            unsigned m3 = xw16[(size_t)v3 * (C / 2) + lane];
            ax = fmaf(w0, bf_lo(m0), ax); ay = fmaf(w0, bf_hi(m0), ay);
            ax = fmaf(w1, bf_lo(m1), ax); ay = fmaf(w1, bf_hi(m1), ay);
            ax = fmaf(w2, bf_lo(m2), ax); ay = fmaf(w2, bf_hi(m2), ay);
            ax = fmaf(w3, bf_lo(m3), ax); ay = fmaf(w3, bf_hi(m3), ay);
        }
        for (; jj < cnt; ++jj) {
            int vv = __shfl(v, jj);
            float w = du * __shfl(dv, jj);
            unsigned m = xw16[(size_t)vv * (C / 2) + lane];
            ax = fmaf(w, bf_lo(m), ax);
            ay = fmaf(w, bf_hi(m), ay);
        }
    }
    float2 o = {ax, ay};
    *(float2*)(out + (size_t)u * C + 2 * lane) = o;
}

// ---------------------------------------------------------------- launch ---
extern "C" void kernel_launch(void* const* d_in, const int* in_sizes, int n_in,
                              void* d_out, int out_size, void* d_ws, size_t ws_size,
                              hipStream_t stream) {
    const float* x  = (const float*)d_in[0];
    const float* W  = (const float*)d_in[1];
    const float* b  = (const float*)d_in[2];
    const int*   ei = (const int*)d_in[3];
    float* out = (float*)d_out;

    // workspace: xw16 [N*64 u32] | deg [N] | gcount [256] | dinv [N] |
    //            rowptr [N+4] | part [512] | staging [64*CAP uint2] | adj [2E]
    char* p = (char*)d_ws;
    unsigned* xw16 = (unsigned*)p;  p += (size_t)N * (C / 2) * sizeof(unsigned);
    int* deg = (int*)p;             p += (size_t)N * sizeof(int);
    int* gcount = (int*)p;          p += 256 * sizeof(int);
    float* dinv = (float*)p;        p += (size_t)N * sizeof(float);
    int* rowptr = (int*)p;          p += (size_t)(N + 4) * sizeof(int);
    int* part = (int*)p;            p += 512 * sizeof(int);
    uint2* staging = (uint2*)p;     p += (size_t)NBUCK * CAP * sizeof(uint2);
    int* adj = (int*)p;

    // zero deg + gcount in one memset (contiguous)
    hipMemsetAsync(deg, 0, (N + 256) * sizeof(int), stream);
    k_bin<<<1563, 256, 0, stream>>>(ei, deg, gcount, staging);
    k_part<<<NBLK, 256, 0, stream>>>(deg, dinv, part);
    k_scan_part<<<1, 512, 0, stream>>>(part);
    k_rowptr<<<NBLK, 256, 0, stream>>>(deg, part, rowptr);
    k_fill2<<<2048, 256, 0, stream>>>(staging, gcount, rowptr, adj);
    k_gemm<<<(N + 63) / 64, 256, 0, stream>>>(x, W, xw16);
    k_gather<<<(N + 3) / 4, 256, 0, stream>>>(rowptr, deg, dinv, adj, xw16, b, out);
}

// Round 7
// 356.151 us; speedup vs baseline: 8.0163x; 1.4563x over previous
//
#include <hip/hip_runtime.h>
#include <math.h>

constexpr int N = 100000;
constexpr int E = 1600000;
constexpr int C = 128;
constexpr int NBUCK = 64;                        // dest buckets for CSR build
constexpr int NPB   = (N + NBUCK - 1) / NBUCK;   // 1563 nodes per bucket
constexpr int CAP   = 53248;                     // staging cap/bucket (mean 50000, +14 sigma)

__device__ inline unsigned f2bf(float f) {   // fp32 -> bf16 bits, RNE
    unsigned u = __float_as_uint(f);
    return (u + 0x7fffu + ((u >> 16) & 1u)) >> 16;
}
__device__ inline unsigned pack2(float lo, float hi) {
    return f2bf(lo) | (f2bf(hi) << 16);
}
__device__ inline float bf_lo(unsigned m) { return __uint_as_float(m << 16); }
__device__ inline float bf_hi(unsigned m) { return __uint_as_float(m & 0xffff0000u); }

// ------------------------------------------------------------- bin pass ----
// One pass over the edge list; NO per-node global atomics (deg is computed
// per-bucket in k_csr). Entry packed to 4 B: (dst_local<<17)|src (11+17 bits).
// Per 2048-edge tile: LDS bucket counts -> one global atomic per bucket ->
// dense appends (~256 B/bucket/tile). Global atomics: 64 * 782 = 50K total.
__global__ __launch_bounds__(256) void k_bin(const int* __restrict__ ei,
                                             int* __restrict__ gcount,
                                             unsigned* __restrict__ staging) {
    __shared__ int cnt[NBUCK];
    __shared__ int wbase[NBUCK];
    const int t = threadIdx.x;
    const long tile = (long)blockIdx.x * 2048;
    if (t < NBUCK) cnt[t] = 0;
    __syncthreads();
    int b0[8], b1[8], lo0[8], lo1[8];
    unsigned p0[8], p1[8];
    bool val[8];
#pragma unroll
    for (int j = 0; j < 8; ++j) {
        long e = tile + j * 256 + t;
        val[j] = e < E;
        if (val[j]) {
            int u = __builtin_nontemporal_load(ei + e);
            int v = __builtin_nontemporal_load(ei + E + e);
            b0[j] = u / NPB;
            b1[j] = v / NPB;
            p0[j] = ((unsigned)(u - b0[j] * NPB) << 17) | (unsigned)v;
            p1[j] = ((unsigned)(v - b1[j] * NPB) << 17) | (unsigned)u;
            lo0[j] = atomicAdd(&cnt[b0[j]], 1);
            lo1[j] = atomicAdd(&cnt[b1[j]], 1);
        }
    }
    __syncthreads();
    if (t < NBUCK) wbase[t] = atomicAdd(&gcount[t], cnt[t]);
    __syncthreads();
#pragma unroll
    for (int j = 0; j < 8; ++j) {
        if (val[j]) {
            staging[(size_t)b0[j] * CAP + wbase[b0[j]] + lo0[j]] = p0[j];
            staging[(size_t)b1[j] * CAP + wbase[b1[j]] + lo1[j]] = p1[j];
        }
    }
}

// -------------------------------------------------- per-bucket CSR build ---
// One 512-thread WG per bucket. Pass 1: LDS histogram -> deg/dinv/rowptr
// (dense writes). In-LDS exclusive scan. Pass 2: LDS cursor atomics -> adj
// slice (200 KB). Zero global atomics.
__global__ __launch_bounds__(512) void k_csr(const unsigned* __restrict__ staging,
                                             const int* __restrict__ gcount,
                                             int* __restrict__ deg,
                                             float* __restrict__ dinv,
                                             int* __restrict__ rowptr,
                                             int* __restrict__ adj) {
    __shared__ int hist[2049];
    __shared__ int wpart[8];
    __shared__ int sh_base;
    const int g = blockIdx.x;
    const int t = threadIdx.x;
    const int cnt = gcount[g];
    if (t == 0) {
        int s = 0;
        for (int i = 0; i < g; ++i) s += gcount[i];
        sh_base = s;
    }
    for (int i = t; i < 2049; i += 512) hist[i] = 0;
    __syncthreads();
    const unsigned* base = staging + (size_t)g * CAP;
    // pass 1: histogram of local dest ids
    for (int i = t; i < cnt; i += 512) atomicAdd(&hist[base[i] >> 17], 1);
    __syncthreads();
    // exclusive scan of hist[0..2048): 4 slots/thread + wave scan + 8 partials
    const int i4 = t * 4;
    const int a0 = hist[i4], a1 = hist[i4 + 1], a2 = hist[i4 + 2], a3 = hist[i4 + 3];
    const int s = a0 + a1 + a2 + a3;
    const int lane = t & 63, wid = t >> 6;
    int v = s;
#pragma unroll
    for (int off = 1; off < 64; off <<= 1) {
        int n = __shfl_up(v, off);
        if (lane >= off) v += n;
    }
    if (lane == 63) wpart[wid] = v;
    __syncthreads();
    if (t == 0) {
        int r = 0;
#pragma unroll
        for (int w = 0; w < 8; ++w) { int x = wpart[w]; wpart[w] = r; r += x; }
    }
    __syncthreads();
    const int excl = v - s + wpart[wid];
    hist[i4]     = excl;
    hist[i4 + 1] = excl + a0;
    hist[i4 + 2] = excl + a0 + a1;
    hist[i4 + 3] = excl + a0 + a1 + a2;
    __syncthreads();
    // dense deg/dinv/rowptr writes for this bucket's nodes
    const int nbase = g * NPB;
    const int nlocal = min(NPB, N - nbase);
    const int bbase = sh_base;
    for (int i = t; i < nlocal; i += 512) {
        int st = hist[i], en = hist[i + 1];
        int d = en - st;
        deg[nbase + i] = d;
        dinv[nbase + i] = rsqrtf((float)d + 1.0f);
        rowptr[nbase + i] = bbase + st;
    }
    __syncthreads();
    // pass 2: fill adj via LDS cursors
    int* aslice = adj + bbase;
    for (int i = t; i < cnt; i += 512) {
        unsigned e = base[i];
        int pos = atomicAdd(&hist[e >> 17], 1);
        aslice[pos] = (int)(e & 0x1ffffu);
    }
}

// ------------------------------------------------------------------ GEMM ---
// xw16 = bf16(x @ W). Self-loop/bias handled in the gather.
__global__ __launch_bounds__(256) void k_gemm(const float* __restrict__ x,
                                              const float* __restrict__ W,
                                              unsigned* __restrict__ xw16) {
    __shared__ float Ws[32][128];
    __shared__ float xs[64][33];

    const int t   = threadIdx.x;
    const int r0  = (t & 15) * 4;
    const int c0  = (t >> 4) * 8;
    const int bid = blockIdx.x;

    float acc[4][8];
#pragma unroll
    for (int i = 0; i < 4; ++i)
#pragma unroll
        for (int j = 0; j < 8; ++j) acc[i][j] = 0.0f;

    const int lrow = t >> 2;
    const int lk   = (t & 3) * 8;
    const long grow = (long)bid * 64 + lrow;
    const bool rvalid = grow < N;

    for (int k0 = 0; k0 < C; k0 += 32) {
        const float4* Wg = (const float4*)(W + (size_t)k0 * C);
        float4* Wsv = (float4*)(&Ws[0][0]);
#pragma unroll
        for (int j = 0; j < 4; ++j) Wsv[t + 256 * j] = Wg[t + 256 * j];
        float4 a0 = {0, 0, 0, 0}, a1 = {0, 0, 0, 0};
        if (rvalid) {
            a0 = *(const float4*)(x + grow * C + k0 + lk);
            a1 = *(const float4*)(x + grow * C + k0 + lk + 4);
        }
        xs[lrow][lk + 0] = a0.x; xs[lrow][lk + 1] = a0.y;
        xs[lrow][lk + 2] = a0.z; xs[lrow][lk + 3] = a0.w;
        xs[lrow][lk + 4] = a1.x; xs[lrow][lk + 5] = a1.y;
        xs[lrow][lk + 6] = a1.z; xs[lrow][lk + 7] = a1.w;
        __syncthreads();

#pragma unroll 8
        for (int k = 0; k < 32; ++k) {
            float4 w0 = *(const float4*)&Ws[k][c0];
            float4 w1 = *(const float4*)&Ws[k][c0 + 4];
            float xv[4];
#pragma unroll
            for (int i = 0; i < 4; ++i) xv[i] = xs[r0 + i][k];
#pragma unroll
            for (int i = 0; i < 4; ++i) {
                acc[i][0] = fmaf(xv[i], w0.x, acc[i][0]);
                acc[i][1] = fmaf(xv[i], w0.y, acc[i][1]);
                acc[i][2] = fmaf(xv[i], w0.z, acc[i][2]);
                acc[i][3] = fmaf(xv[i], w0.w, acc[i][3]);
                acc[i][4] = fmaf(xv[i], w1.x, acc[i][4]);
                acc[i][5] = fmaf(xv[i], w1.y, acc[i][5]);
                acc[i][6] = fmaf(xv[i], w1.z, acc[i][6]);
                acc[i][7] = fmaf(xv[i], w1.w, acc[i][7]);
            }
        }
        __syncthreads();
    }

#pragma unroll
    for (int i = 0; i < 4; ++i) {
        long r = (long)bid * 64 + r0 + i;
        if (r >= N) break;
        uint4 pk = {pack2(acc[i][0], acc[i][1]), pack2(acc[i][2], acc[i][3]),
                    pack2(acc[i][4], acc[i][5]), pack2(acc[i][6], acc[i][7])};
        *(uint4*)(xw16 + r * (C / 2) + (c0 >> 1)) = pk;
    }
}

// ---------------------------------------------------------------- gather ---
// One wave per node; lane owns channels 2*lane, 2*lane+1. Self-loop + bias
// fused. rowptr holds segment START now (k_csr writes clean rowptrs).
__global__ __launch_bounds__(256) void k_gather(const int* __restrict__ rowptr,
                                                const int* __restrict__ deg,
                                                const float* __restrict__ dinv,
                                                const int* __restrict__ adj,
                                                const unsigned* __restrict__ xw16,
                                                const float* __restrict__ b,
                                                float* __restrict__ out) {
    int u = blockIdx.x * 4 + (threadIdx.x >> 6);
    if (u >= N) return;
    const int lane = threadIdx.x & 63;
    const int d = deg[u];
    const int start = rowptr[u];
    const float du = dinv[u];
    // self-loop + bias
    const unsigned ms = xw16[(size_t)u * (C / 2) + lane];
    const float2 bb = *(const float2*)(b + 2 * lane);
    const float s2 = du * du;
    float ax = fmaf(s2, bf_lo(ms), bb.x);
    float ay = fmaf(s2, bf_hi(ms), bb.y);

    for (int j0 = 0; j0 < d; j0 += 64) {
        int v = 0;
        float dv = 0.f;
        if (j0 + lane < d) {
            v = adj[start + j0 + lane];
            dv = dinv[v];
        }
        const int cnt = min(64, d - j0);
        int jj = 0;
        for (; jj + 4 <= cnt; jj += 4) {
            int v0 = __shfl(v, jj),     v1 = __shfl(v, jj + 1);
            int v2 = __shfl(v, jj + 2), v3 = __shfl(v, jj + 3);
            float w0 = du * __shfl(dv, jj),     w1 = du * __shfl(dv, jj + 1);
            float w2 = du * __shfl(dv, jj + 2), w3 = du * __shfl(dv, jj + 3);
            unsigned m0 = xw16[(size_t)v0 * (C / 2) + lane];
            unsigned m1 = xw16[(size_t)v1 * (C / 2) + lane];
            unsigned m2 = xw16[(size_t)v2 * (C / 2) + lane];
            unsigned m3 = xw16[(size_t)v3 * (C / 2) + lane];
            ax = fmaf(w0, bf_lo(m0), ax); ay = fmaf(w0, bf_hi(m0), ay);
            ax = fmaf(w1, bf_lo(m1), ax); ay = fmaf(w1, bf_hi(m1), ay);
            ax = fmaf(w2, bf_lo(m2), ax); ay = fmaf(w2, bf_hi(m2), ay);
            ax = fmaf(w3, bf_lo(m3), ax); ay = fmaf(w3, bf_hi(m3), ay);
        }
        for (; jj < cnt; ++jj) {
            int vv = __shfl(v, jj);
            float w = du * __shfl(dv, jj);
            unsigned m = xw16[(size_t)vv * (C / 2) + lane];
            ax = fmaf(w, bf_lo(m), ax);
            ay = fmaf(w, bf_hi(m), ay);
        }
    }
    float2 o = {ax, ay};
    *(float2*)(out + (size_t)u * C + 2 * lane) = o;
}

// ---------------------------------------------------------------- launch ---
extern "C" void kernel_launch(void* const* d_in, const int* in_sizes, int n_in,
                              void* d_out, int out_size, void* d_ws, size_t ws_size,
                              hipStream_t stream) {
    const float* x  = (const float*)d_in[0];
    const float* W  = (const float*)d_in[1];
    const float* b  = (const float*)d_in[2];
    const int*   ei = (const int*)d_in[3];
    float* out = (float*)d_out;

    // workspace: xw16 [N*64 u32] | deg [N] | dinv [N] | rowptr [N+4] |
    //            gcount [256] | staging [64*CAP u32] | adj [2E]
    char* p = (char*)d_ws;
    unsigned* xw16 = (unsigned*)p;  p += (size_t)N * (C / 2) * sizeof(unsigned);
    int* deg = (int*)p;             p += (size_t)N * sizeof(int);
    float* dinv = (float*)p;        p += (size_t)N * sizeof(float);
    int* rowptr = (int*)p;          p += (size_t)(N + 4) * sizeof(int);
    int* gcount = (int*)p;          p += 256 * sizeof(int);
    unsigned* staging = (unsigned*)p; p += (size_t)NBUCK * CAP * sizeof(unsigned);
    int* adj = (int*)p;

    hipMemsetAsync(gcount, 0, 256 * sizeof(int), stream);
    k_bin<<<(E + 2047) / 2048, 256, 0, stream>>>(ei, gcount, staging);
    k_csr<<<NBUCK, 512, 0, stream>>>(staging, gcount, deg, dinv, rowptr, adj);
    k_gemm<<<(N + 63) / 64, 256, 0, stream>>>(x, W, xw16);
    k_gather<<<(N + 3) / 4, 256, 0, stream>>>(rowptr, deg, dinv, adj, xw16, b, out);
}